// Round 1
// baseline (2083.493 us; speedup 1.0000x reference)
//
#include <hip/hip_runtime.h>
#include <math.h>

// Sinkhorn iteration: m = diag(r) * M0 * diag(c) throughout.
// M0 = exp(x - rowmax) stored in d_out (reused as scratch, overwritten at end).
// ws layout: r[16384] | c[16384] | vpart[PCHUNK][16384]  (~2.2 MB)

#define EPSV 1e-6f
#define NDIM 4096
#define NB 4
#define NROWS (NB * NDIM)        // 16384
#define SINKHORN_ITERS 20
#define PCHUNK 32                // row-chunks in column pass
#define ROWS_PER_CHUNK (NDIM / PCHUNK)  // 128

// ---- init: M0 = exp(x - rowmax), r = c = 1 --------------------------------
__global__ __launch_bounds__(256) void init_kernel(
    const float* __restrict__ x, float* __restrict__ m0,
    float* __restrict__ r, float* __restrict__ c) {
  const int row = blockIdx.x;              // 0..16383
  const int t = threadIdx.x;               // 0..255
  const float4* xr = (const float4*)(x + (size_t)row * NDIM);
  float4* mr = (float4*)(m0 + (size_t)row * NDIM);

  float4 vals[4];
  float mx = -INFINITY;
#pragma unroll
  for (int k = 0; k < 4; k++) {
    vals[k] = xr[k * 256 + t];
    mx = fmaxf(mx, fmaxf(fmaxf(vals[k].x, vals[k].y), fmaxf(vals[k].z, vals[k].w)));
  }
  // block max reduce (4 waves of 64)
  __shared__ float sdata[4];
  const int lane = t & 63, wid = t >> 6;
#pragma unroll
  for (int o = 32; o > 0; o >>= 1) mx = fmaxf(mx, __shfl_down(mx, o, 64));
  if (lane == 0) sdata[wid] = mx;
  __syncthreads();
  const float bmax = fmaxf(fmaxf(sdata[0], sdata[1]), fmaxf(sdata[2], sdata[3]));

#pragma unroll
  for (int k = 0; k < 4; k++) {
    float4 e;
    e.x = __expf(vals[k].x - bmax);
    e.y = __expf(vals[k].y - bmax);
    e.z = __expf(vals[k].z - bmax);
    e.w = __expf(vals[k].w - bmax);
    mr[k * 256 + t] = e;
  }
  if (t == 0) { r[row] = 1.0f; c[row] = 1.0f; }
}

// ---- row pass: u = M0 @ c per row; r <- r/(r*u+eps) -----------------------
__global__ __launch_bounds__(256) void row_kernel(
    const float* __restrict__ m0, const float* __restrict__ c,
    float* __restrict__ r) {
  const int row = blockIdx.x;              // 0..16383
  const int b = row >> 12;
  const int t = threadIdx.x;
  const float4* mr = (const float4*)(m0 + (size_t)row * NDIM);
  const float4* cb = (const float4*)(c + b * NDIM);

  float dot = 0.f;
#pragma unroll
  for (int k = 0; k < 4; k++) {
    float4 a = mr[k * 256 + t];
    float4 cc = cb[k * 256 + t];
    dot += a.x * cc.x + a.y * cc.y + a.z * cc.z + a.w * cc.w;
  }
  __shared__ float sdata[4];
  const int lane = t & 63, wid = t >> 6;
#pragma unroll
  for (int o = 32; o > 0; o >>= 1) dot += __shfl_down(dot, o, 64);
  if (lane == 0) sdata[wid] = dot;
  __syncthreads();
  if (t == 0) {
    const float u = sdata[0] + sdata[1] + sdata[2] + sdata[3];
    const float rr = r[row];
    r[row] = rr / (rr * u + EPSV);
  }
}

// ---- col pass: partial column sums weighted by r --------------------------
// grid: (NB, 4 colchunks of 1024 cols, PCHUNK row-chunks of 128 rows)
__global__ __launch_bounds__(256) void col_kernel(
    const float* __restrict__ m0, const float* __restrict__ r,
    float* __restrict__ vpart) {
  const int b = blockIdx.x;
  const int cc = blockIdx.y;
  const int p = blockIdx.z;
  const int t = threadIdx.x;
  const int j = cc * 1024 + t * 4;         // 4 consecutive cols per thread
  const float* mb = m0 + (size_t)b * NDIM * NDIM;
  const float* rb = r + b * NDIM;
  const int i0 = p * ROWS_PER_CHUNK;

  float4 acc0 = {0.f, 0.f, 0.f, 0.f};
  float4 acc1 = {0.f, 0.f, 0.f, 0.f};
#pragma unroll 2
  for (int i = i0; i < i0 + ROWS_PER_CHUNK; i += 2) {
    float4 a0 = *(const float4*)(mb + (size_t)i * NDIM + j);
    float4 a1 = *(const float4*)(mb + (size_t)(i + 1) * NDIM + j);
    const float r0 = rb[i];
    const float r1 = rb[i + 1];
    acc0.x += a0.x * r0; acc0.y += a0.y * r0; acc0.z += a0.z * r0; acc0.w += a0.w * r0;
    acc1.x += a1.x * r1; acc1.y += a1.y * r1; acc1.z += a1.z * r1; acc1.w += a1.w * r1;
  }
  float4 acc;
  acc.x = acc0.x + acc1.x; acc.y = acc0.y + acc1.y;
  acc.z = acc0.z + acc1.z; acc.w = acc0.w + acc1.w;
  *(float4*)(vpart + (size_t)p * NROWS + b * NDIM + j) = acc;
}

// ---- c update: v = sum of partials; c <- c/(c*v+eps) ----------------------
__global__ __launch_bounds__(256) void cupdate_kernel(
    const float* __restrict__ vpart, float* __restrict__ c) {
  const int idx = blockIdx.x * 256 + threadIdx.x;  // 0..16383
  float v = 0.f;
#pragma unroll
  for (int p = 0; p < PCHUNK; p++) v += vpart[p * NROWS + idx];
  const float cc = c[idx];
  c[idx] = cc / (cc * v + EPSV);
}

// ---- final: out = M0 * r(i) * c(j), in place over d_out -------------------
__global__ __launch_bounds__(256) void final_kernel(
    float* __restrict__ m0, const float* __restrict__ r,
    const float* __restrict__ c) {
  const size_t idx = (size_t)blockIdx.x * 256 + threadIdx.x;  // per float4
  const size_t flat = idx * 4;
  const int row = (int)(flat >> 12);
  const int b = row >> 12;
  const int jj = (int)(flat & 4095);
  float4 m = ((float4*)m0)[idx];
  const float rv = r[row];
  const float4 cv = *(const float4*)(c + b * NDIM + jj);
  m.x *= rv * cv.x;
  m.y *= rv * cv.y;
  m.z *= rv * cv.z;
  m.w *= rv * cv.w;
  ((float4*)m0)[idx] = m;
}

extern "C" void kernel_launch(void* const* d_in, const int* in_sizes, int n_in,
                              void* d_out, int out_size, void* d_ws, size_t ws_size,
                              hipStream_t stream) {
  const float* x = (const float*)d_in[0];
  float* m0 = (float*)d_out;               // d_out doubles as M0 scratch
  float* r = (float*)d_ws;
  float* c = r + NROWS;
  float* vpart = c + NROWS;                // PCHUNK * NROWS floats

  init_kernel<<<NROWS, 256, 0, stream>>>(x, m0, r, c);

  for (int it = 0; it < SINKHORN_ITERS; it++) {
    row_kernel<<<NROWS, 256, 0, stream>>>(m0, c, r);
    dim3 g(NB, 4, PCHUNK);
    col_kernel<<<g, 256, 0, stream>>>(m0, r, vpart);
    cupdate_kernel<<<NROWS / 256, 256, 0, stream>>>(vpart, c);
  }

  const int n_f4 = NROWS * NDIM / 4;       // 16,777,216 float4
  final_kernel<<<n_f4 / 256, 256, 0, stream>>>(m0, r, c);
}